// Round 1
// baseline (243.141 us; speedup 1.0000x reference)
//
#include <hip/hip_runtime.h>

namespace {

constexpr int   kT     = 512;
constexpr int   kC     = 512;
constexpr int   kL     = 128;
constexpr int   kS     = 2 * kL + 1;   // 257 extended states
constexpr int   kBlank = kC - 1;       // 511
constexpr int   kNBuf  = 8;            // row ring depth (power of 2)
constexpr float kNeg   = -1e30f;
constexpr float kEps   = 1e-7f;

typedef float __attribute__((address_space(1))) f32g;
typedef float __attribute__((address_space(3))) f32l;

__device__ __forceinline__ void load_row16(const float* g, float* lds) {
    // 16B per lane, wave-uniform LDS base + lane*16 (HW rule), per-lane global addr.
    __builtin_amdgcn_global_load_lds((const f32g*)g, (f32l*)lds, 16, 0, 0);
}

__device__ __forceinline__ void ring_barrier() {
    // Keep up to 6 row-loads in flight across the barrier (counted vmcnt);
    // drain LDS ops so alpha writes are visible to all waves after the barrier.
    asm volatile("s_waitcnt vmcnt(6) lgkmcnt(0)" ::: "memory");
    __builtin_amdgcn_s_barrier();
    asm volatile("" ::: "memory");
}

__global__ __launch_bounds__(320, 1) void ctc_fwd_kernel(
        const int* __restrict__ labels,
        const float* __restrict__ y_pred,
        float* __restrict__ out) {
    __shared__ __align__(16) float rowbuf[kNBuf][kC];   // 16 KiB ring of prob rows
    __shared__ float alphaBuf[2][kS + 2];               // 2 leading -inf pad slots

    const int tid  = (int)threadIdx.x;
    const int b    = (int)blockIdx.x;
    const int lane = tid & 63;
    const int wv   = tid >> 6;
    const float* yp = y_pred + (size_t)b * kT * kC;

    // ---- per-thread label constants (state s = tid) ----
    int l1 = 0, l2 = 0;
    if (tid < kS) {
        const int i1 = (tid >= 1) ? ((tid - 1) >> 1) : 0;
        const int i2 = (tid >= 3) ? ((tid - 3) >> 1) : 0;
        l1 = labels[b * kL + i1];
        l2 = labels[b * kL + i2];
    }

    // ---- issue rows 0..7 into the ring (waves 0,1 stage 1 KiB each) ----
    if (tid < 128) {
        const float* g = yp + wv * 256 + lane * 4;
#pragma unroll
        for (int r = 0; r < kNBuf; ++r)
            load_row16(g + r * kC, &rowbuf[r][wv * 256]);
    }

    const int  eclass = (tid & 1) ? l1 : kBlank;                    // ext[s]
    const bool skipf  = (tid & 1) && (tid >= 3) && (l1 != l2);      // skip transition

    ring_barrier();   // rows 0,1 guaranteed complete past this point

    // ---- t = 0 init: alpha0[0]=lp(blank), alpha0[1]=lp(label0), else -inf ----
    if (tid < kS) {
        float a0 = kNeg;
        if (tid < 2) a0 = __logf(rowbuf[0][eclass] + kEps);
        alphaBuf[0][tid + 2] = a0;
    }
    if (tid < 2) { alphaBuf[0][tid] = kNeg; alphaBuf[1][tid] = kNeg; }
    ring_barrier();

    // ---- forward recursion over t = 1..T-1, one barrier per step ----
    for (int t = 1; t < kT; ++t) {
        const int p = t & 1;
        if (tid < 128) {
            int rr = t + 7; if (rr > kT - 1) rr = kT - 1;   // clamped tail prefetch
            load_row16(yp + (size_t)rr * kC + wv * 256 + lane * 4,
                       &rowbuf[(t + 7) & (kNBuf - 1)][wv * 256]);
        }
        if (tid < kS) {
            const float* row  = rowbuf[t & (kNBuf - 1)];
            const float* aOld = alphaBuf[p ^ 1];
            const float lp = __logf(row[eclass] + kEps);
            const float a  = aOld[tid + 2];
            const float bb = aOld[tid + 1];
            const float cc = skipf ? aOld[tid] : kNeg;
            const float m  = fmaxf(fmaxf(a, bb), cc);
            const float s  = __expf(a - m) + __expf(bb - m) + __expf(cc - m);
            alphaBuf[p][tid + 2] = m + __logf(s) + lp;
        }
        ring_barrier();
    }

    // ---- loss = -logaddexp(alpha[S-1], alpha[S-2]) ----
    if (tid == 0) {
        const float* aF = alphaBuf[(kT - 1) & 1];
        const float a  = aF[kS + 1];   // state S-1
        const float bb = aF[kS];       // state S-2
        const float m  = fmaxf(a, bb);
        out[b] = -(m + __logf(__expf(a - m) + __expf(bb - m)));
    }
}

} // namespace

extern "C" void kernel_launch(void* const* d_in, const int* in_sizes, int n_in,
                              void* d_out, int out_size, void* d_ws, size_t ws_size,
                              hipStream_t stream) {
    const int*   labels = (const int*)d_in[0];   // y_true [256,128] int32
    const float* y_pred = (const float*)d_in[1]; // y_pred [256,512,512] f32
    float*       out    = (float*)d_out;         // loss [256,1] f32
    (void)in_sizes; (void)n_in; (void)d_ws; (void)ws_size;
    hipLaunchKernelGGL(ctc_fwd_kernel, dim3(out_size), dim3(320), 0, stream,
                       labels, y_pred, out);
}